// Round 2
// baseline (789.500 us; speedup 1.0000x reference)
//
#include <hip/hip_runtime.h>

typedef __bf16 bf16_t;
typedef __bf16 bf16x8 __attribute__((ext_vector_type(8)));
typedef __bf16 bf16x4 __attribute__((ext_vector_type(4)));
typedef float  f32x4  __attribute__((ext_vector_type(4)));

#define MFMA16(a,b,c) __builtin_amdgcn_mfma_f32_16x16x32_bf16((a),(b),(c),0,0,0)

// Two windows per block. LDS plan (bf16 elems), total 30966 -> 61,932 B -> 2 blocks/CU:
//   region[w] [13056]: x_w [64][200] ->(barrier)-> vT_w [192][68] ->(barrier)-> attn_w [64][200]
//   scratch: per-wave [16][40] chunk (Q/K/P roundtrips, one 16-row band at a time;
//            same-wave DS ordering makes barrier-free reuse safe)
//   bt [1014]: rel-bias table (shared by both windows)
// Rationale: each weight fragment now feeds 16 MFMAs (both windows) -> weight-load
// count and exposed L2/L3 latency per window halved; barriers per window halved.
#define REG_STRIDE 200
#define VT_STRIDE  68
#define REG_ELEMS  13056
#define SC_STRIDE  40
#define SC_CHUNK   640                         // [16][40]
#define SC_OFF     (2 * REG_ELEMS)             // 26112
#define BT_OFF     (SC_OFF + 6 * SC_CHUNK)     // 29952
#define SMEM_ELEMS (BT_OFF + 1014)             // 30966 elems = 61,932 B

// bf16 weights staged in workspace by prep kernel: qkv_w [576*192] then proj_w [192*192]
#define WPROJ_OFF 110592

__global__ void convert_w_kernel(const float* __restrict__ qkv_w,
                                 const float* __restrict__ proj_w,
                                 bf16_t* __restrict__ wb) {
    const int i = (blockIdx.x * 256 + threadIdx.x) * 4;
    float4 f;
    if (i < WPROJ_OFF) f = *(const float4*)(qkv_w + i);
    else               f = *(const float4*)(proj_w + (i - WPROJ_OFF));
    bf16x4 v;
    v[0] = (bf16_t)f.x; v[1] = (bf16_t)f.y; v[2] = (bf16_t)f.z; v[3] = (bf16_t)f.w;
    *(bf16x4*)(wb + i) = v;
}

// Paired 64x32 GEMM over K=192 for two windows sharing the same weight fragments.
// A-frags from LDS (row-major, REG_STRIDE); B-frags from bf16 weight rows, depth-2
// rolling prefetch. 16 MFMAs per prefetch step (vs 8 single-window).
__device__ __forceinline__ void gemm2(const bf16_t* __restrict__ xaA,
                                      const bf16_t* __restrict__ xaB,
                                      const bf16_t* __restrict__ w0,
                                      const bf16_t* __restrict__ w1,
                                      f32x4 accA[4][2], f32x4 accB[4][2]) {
    bf16x8 b0 = *(const bf16x8*)(w0);
    bf16x8 b1 = *(const bf16x8*)(w1);
    bf16x8 n0 = *(const bf16x8*)(w0 + 32);
    bf16x8 n1 = *(const bf16x8*)(w1 + 32);
    #pragma unroll
    for (int ks = 0; ks < 6; ++ks) {
        bf16x8 m0, m1;
        if (ks < 4) {
            m0 = *(const bf16x8*)(w0 + (ks + 2) * 32);
            m1 = *(const bf16x8*)(w1 + (ks + 2) * 32);
        }
        #pragma unroll
        for (int mi = 0; mi < 4; ++mi) {
            const bf16x8 aA = *(const bf16x8*)(xaA + (mi * 16) * REG_STRIDE + ks * 32);
            accA[mi][0] = MFMA16(aA, b0, accA[mi][0]);
            accA[mi][1] = MFMA16(aA, b1, accA[mi][1]);
        }
        #pragma unroll
        for (int mi = 0; mi < 4; ++mi) {
            const bf16x8 aB = *(const bf16x8*)(xaB + (mi * 16) * REG_STRIDE + ks * 32);
            accB[mi][0] = MFMA16(aB, b0, accB[mi][0]);
            accB[mi][1] = MFMA16(aB, b1, accB[mi][1]);
        }
        b0 = n0; b1 = n1; n0 = m0; n1 = m1;
    }
}

// acc -> bf16 scratch roundtrip (per-mi 16-row band) -> MFMA A/B-frag layout
__device__ __forceinline__ void roundtrip(bf16_t* __restrict__ sc, int lanelo, int quad,
                                          const f32x4 acc[4][2], float bias0, float bias1,
                                          bf16x8 outfr[4]) {
    #pragma unroll
    for (int mi = 0; mi < 4; ++mi) {
        #pragma unroll
        for (int r = 0; r < 4; ++r) {
            sc[(quad * 4 + r) * SC_STRIDE + lanelo]      = (bf16_t)(acc[mi][0][r] + bias0);
            sc[(quad * 4 + r) * SC_STRIDE + 16 + lanelo] = (bf16_t)(acc[mi][1][r] + bias1);
        }
        outfr[mi] = *(const bf16x8*)(sc + lanelo * SC_STRIDE + quad * 8);
    }
}

__global__ __launch_bounds__(384, 3)
void swin_fused_kernel(const float* __restrict__ x,
                       const bf16_t* __restrict__ wbuf,
                       const float* __restrict__ qkv_b,
                       const float* __restrict__ proj_b,
                       const float* __restrict__ tbl,
                       float* __restrict__ out)
{
    __shared__ __align__(16) bf16_t smem[SMEM_ELEMS];
    bf16_t* bt = smem + BT_OFF;

    const int tid    = threadIdx.x;
    const int lane   = tid & 63;
    const int wave   = tid >> 6;        // == head
    const int lanelo = lane & 15;
    const int quad   = lane >> 4;

    bf16_t* sc = smem + SC_OFF + wave * SC_CHUNK;   // per-wave [16][40]

    // pair of windows: blk2 = blk*2 + w; pair shares b, wh (only bit0 of ww differs)
    const int blk = blockIdx.x;
    const int b   = blk >> 7;
    const int wh  = (blk >> 3) & 15;
    const int ww0 = (blk & 7) * 2;
    const int rowbase  = wh * 7 + 3;    // shifted (i) -> orig (i+3)%112
    const int colbase0 = ww0 * 7 + 3;

    // ---- phase 0: bias table + both x windows -> LDS bf16 (rows 49..63 zeroed) ----
    for (int i = tid; i < 1014; i += 384) bt[i] = (bf16_t)tbl[i];

    #pragma unroll
    for (int w = 0; w < 2; ++w) {
        bf16_t* reg = smem + w * REG_ELEMS;
        const int cb = colbase0 + w * 7;
        #pragma unroll 4
        for (int it = 0; it < 8; ++it) {
            const int idx = tid + it * 384;
            const int t  = idx / 48;
            const int c4 = (idx - t * 48) * 4;
            bf16x4 v4;
            if (t < 49) {
                int gr = rowbase + t / 7;  if (gr >= 112) gr -= 112;
                int gc = cb + t % 7;       if (gc >= 112) gc -= 112;
                const float4 f = *(const float4*)(x + (((long)b * 112 + gr) * 112 + gc) * 192 + c4);
                v4[0] = (bf16_t)f.x; v4[1] = (bf16_t)f.y;
                v4[2] = (bf16_t)f.z; v4[3] = (bf16_t)f.w;
            } else {
                v4[0] = (bf16_t)0.0f; v4[1] = (bf16_t)0.0f;
                v4[2] = (bf16_t)0.0f; v4[3] = (bf16_t)0.0f;
            }
            *(bf16x4*)(reg + t * REG_STRIDE + c4) = v4;
        }
    }
    __syncthreads();

    // ---- phase 1: per-wave head QKV for both windows (V first to shed its accs at
    //      the barrier; Q last so its accs overlap the smallest live set) ----
    const int h = wave;
    const bf16_t* xaA = smem + lanelo * REG_STRIDE + quad * 8;
    const bf16_t* xaB = smem + REG_ELEMS + lanelo * REG_STRIDE + quad * 8;

    f32x4  vacc[2][4][2] = {};
    bf16x8 kb[2][4], qa[2][4];
    // V
    {
        const bf16_t* wb = wbuf + (2 * 192 + h * 32) * 192;
        gemm2(xaA, xaB, wb + lanelo * 192 + quad * 8, wb + (16 + lanelo) * 192 + quad * 8,
              vacc[0], vacc[1]);
    }
    // K
    {
        const bf16_t* wb = wbuf + (1 * 192 + h * 32) * 192;
        f32x4 tacc[2][4][2] = {};
        gemm2(xaA, xaB, wb + lanelo * 192 + quad * 8, wb + (16 + lanelo) * 192 + quad * 8,
              tacc[0], tacc[1]);
        const float b0 = qkv_b[192 + h * 32 + lanelo];
        const float b1 = qkv_b[192 + h * 32 + 16 + lanelo];
        roundtrip(sc, lanelo, quad, tacc[0], b0, b1, kb[0]);
        roundtrip(sc, lanelo, quad, tacc[1], b0, b1, kb[1]);
    }
    // Q
    {
        const bf16_t* wb = wbuf + (0 * 192 + h * 32) * 192;
        f32x4 tacc[2][4][2] = {};
        gemm2(xaA, xaB, wb + lanelo * 192 + quad * 8, wb + (16 + lanelo) * 192 + quad * 8,
              tacc[0], tacc[1]);
        const float b0 = qkv_b[h * 32 + lanelo];
        const float b1 = qkv_b[h * 32 + 16 + lanelo];
        roundtrip(sc, lanelo, quad, tacc[0], b0, b1, qa[0]);
        roundtrip(sc, lanelo, quad, tacc[1], b0, b1, qa[1]);
    }
    __syncthreads();   // all x reads done -> regions become vT

    // vT write: reg[dim][token], stride 68; wave h owns dims h*32..h*32+31
    {
        const float b0 = qkv_b[2 * 192 + h * 32 + lanelo];
        const float b1 = qkv_b[2 * 192 + h * 32 + 16 + lanelo];
        #pragma unroll
        for (int w = 0; w < 2; ++w) {
            bf16_t* reg = smem + w * REG_ELEMS;
            #pragma unroll
            for (int mi = 0; mi < 4; ++mi)
                #pragma unroll
                for (int r = 0; r < 4; ++r) {
                    const int tok = quad * 4 + r + 16 * mi;
                    reg[(h * 32 + lanelo) * VT_STRIDE + tok]      = (bf16_t)(vacc[w][mi][0][r] + b0);
                    reg[(h * 32 + 16 + lanelo) * VT_STRIDE + tok] = (bf16_t)(vacc[w][mi][1][r] + b1);
                }
        }
    }

    // ---- phase 2: per window, S = Q K^T, mask+softmax, chunked P roundtrip, PV ----
    f32x4 o_[2][4][2] = {};
    {
        const float scale = 0.17677669529663687f;   // 32^-0.5

        // window-independent key-column attributes
        int kvalid[4], kch[4], kcw[4];
        #pragma unroll
        for (int ni = 0; ni < 4; ++ni) {
            const int col = ni * 16 + lanelo;
            kvalid[ni] = (col < 49);
            const int cc = kvalid[ni] ? col : 48;
            kch[ni] = cc / 7; kcw[ni] = cc - kch[ni] * 7;
        }

        #pragma unroll
        for (int w = 0; w < 2; ++w) {
            const bf16_t* reg = smem + w * REG_ELEMS;
            const int wwl = ww0 + w;
            int kid[4];
            #pragma unroll
            for (int ni = 0; ni < 4; ++ni) {
                const int gr = wh * 7 + kch[ni], gc = wwl * 7 + kcw[ni];
                kid[ni] = (gr < 105 ? 0 : (gr < 109 ? 1 : 2)) * 3 + (gc < 105 ? 0 : (gc < 109 ? 1 : 2));
            }

            // V fragments (own head rows of vT; written by this same wave above)
            const bf16x8 bv00 = *(const bf16x8*)(reg + (h * 32 + lanelo) * VT_STRIDE + quad * 8);
            const bf16x8 bv01 = *(const bf16x8*)(reg + (h * 32 + 16 + lanelo) * VT_STRIDE + quad * 8);
            const bf16x8 bv10 = *(const bf16x8*)(reg + (h * 32 + lanelo) * VT_STRIDE + 32 + quad * 8);
            const bf16x8 bv11 = *(const bf16x8*)(reg + (h * 32 + 16 + lanelo) * VT_STRIDE + 32 + quad * 8);

            #pragma unroll
            for (int mi = 0; mi < 4; ++mi) {
                f32x4 s[4];
                #pragma unroll
                for (int ni = 0; ni < 4; ++ni) {
                    f32x4 z = {0.f, 0.f, 0.f, 0.f};
                    s[ni] = MFMA16(qa[w][mi], kb[w][ni], z);
                }
                #pragma unroll
                for (int r = 0; r < 4; ++r) {
                    const int row = mi * 16 + quad * 4 + r;
                    const int rq  = (row < 49) ? row : 48;
                    const int rh  = rq / 7, rw = rq - (rq / 7) * 7;
                    const int gqr = wh * 7 + rh, gqc = wwl * 7 + rw;
                    const int idq = (gqr < 105 ? 0 : (gqr < 109 ? 1 : 2)) * 3 + (gqc < 105 ? 0 : (gqc < 109 ? 1 : 2));
                    #pragma unroll
                    for (int ni = 0; ni < 4; ++ni) {
                        float v;
                        if (kvalid[ni]) {
                            const int bidx = ((rh - kch[ni] + 6) * 13 + (rw - kcw[ni] + 6)) * 6 + h;
                            v = s[ni][r] * scale + (float)bt[bidx];
                            if (idq != kid[ni]) v -= 100.0f;
                        } else {
                            v = -1e30f;
                        }
                        s[ni][r] = v;
                    }
                    float m0 = fmaxf(fmaxf(s[0][r], s[1][r]), fmaxf(s[2][r], s[3][r]));
                    m0 = fmaxf(m0, __shfl_xor(m0, 1));
                    m0 = fmaxf(m0, __shfl_xor(m0, 2));
                    m0 = fmaxf(m0, __shfl_xor(m0, 4));
                    m0 = fmaxf(m0, __shfl_xor(m0, 8));
                    float sum = 0.f;
                    #pragma unroll
                    for (int ni = 0; ni < 4; ++ni) {
                        const float e = __expf(s[ni][r] - m0);
                        s[ni][r] = e;
                        sum += e;
                    }
                    sum += __shfl_xor(sum, 1);
                    sum += __shfl_xor(sum, 2);
                    sum += __shfl_xor(sum, 4);
                    sum += __shfl_xor(sum, 8);
                    const float rinv = 1.0f / sum;
                    // P cols 0..31 (ni=0,1) -> chunk now; keep ni=2,3 normalized in regs
                    sc[(quad * 4 + r) * SC_STRIDE + lanelo]      = (bf16_t)(s[0][r] * rinv);
                    sc[(quad * 4 + r) * SC_STRIDE + 16 + lanelo] = (bf16_t)(s[1][r] * rinv);
                    s[2][r] *= rinv;
                    s[3][r] *= rinv;
                }
                {   // PV ks=0
                    const bf16x8 ap = *(const bf16x8*)(sc + lanelo * SC_STRIDE + quad * 8);
                    o_[w][mi][0] = MFMA16(ap, bv00, o_[w][mi][0]);
                    o_[w][mi][1] = MFMA16(ap, bv01, o_[w][mi][1]);
                }
                #pragma unroll
                for (int r = 0; r < 4; ++r) {
                    sc[(quad * 4 + r) * SC_STRIDE + lanelo]      = (bf16_t)s[2][r];
                    sc[(quad * 4 + r) * SC_STRIDE + 16 + lanelo] = (bf16_t)s[3][r];
                }
                {   // PV ks=1
                    const bf16x8 ap = *(const bf16x8*)(sc + lanelo * SC_STRIDE + quad * 8);
                    o_[w][mi][0] = MFMA16(ap, bv10, o_[w][mi][0]);
                    o_[w][mi][1] = MFMA16(ap, bv11, o_[w][mi][1]);
                }
            }
        }
    }
    __syncthreads();   // all vT reads done -> regions become attn_out

    // attn_out write (C-layout), rows = tokens, stride 200
    #pragma unroll
    for (int w = 0; w < 2; ++w) {
        bf16_t* reg = smem + w * REG_ELEMS;
        #pragma unroll
        for (int mi = 0; mi < 4; ++mi)
            #pragma unroll
            for (int r = 0; r < 4; ++r) {
                const int row = quad * 4 + r + 16 * mi;
                reg[row * REG_STRIDE + h * 32 + lanelo]      = (bf16_t)(o_[w][mi][0][r]);
                reg[row * REG_STRIDE + h * 32 + 16 + lanelo] = (bf16_t)(o_[w][mi][1][r]);
            }
    }
    __syncthreads();

    // ---- phase 3: proj GEMM-pair + bias, scatter to output with inverse roll ----
    {
        const bf16_t* wb = wbuf + WPROJ_OFF + (h * 32) * 192;
        f32x4 pacc[2][4][2] = {};
        gemm2(xaA, xaB, wb + lanelo * 192 + quad * 8, wb + (16 + lanelo) * 192 + quad * 8,
              pacc[0], pacc[1]);
        const int o0 = h * 32 + lanelo;
        const int o1 = o0 + 16;
        const float pb0 = proj_b[o0];
        const float pb1 = proj_b[o1];
        #pragma unroll
        for (int w = 0; w < 2; ++w) {
            const int cb = colbase0 + w * 7;
            #pragma unroll
            for (int mi = 0; mi < 4; ++mi)
                #pragma unroll
                for (int r = 0; r < 4; ++r) {
                    const int row = quad * 4 + r + 16 * mi;
                    if (row < 49) {
                        int gr = rowbase + row / 7;  if (gr >= 112) gr -= 112;
                        int gc = cb + row % 7;       if (gc >= 112) gc -= 112;
                        float* op = out + (((long)b * 112 + gr) * 112 + gc) * 192;
                        op[o0] = pacc[w][mi][0][r] + pb0;
                        op[o1] = pacc[w][mi][1][r] + pb1;
                    }
                }
        }
    }
}

extern "C" void kernel_launch(void* const* d_in, const int* in_sizes, int n_in,
                              void* d_out, int out_size, void* d_ws, size_t ws_size,
                              hipStream_t stream) {
    const float* x      = (const float*)d_in[0];
    const float* qkv_w  = (const float*)d_in[1];
    const float* qkv_b  = (const float*)d_in[2];
    const float* proj_w = (const float*)d_in[3];
    const float* proj_b = (const float*)d_in[4];
    const float* tbl    = (const float*)d_in[5];
    bf16_t* wbuf = (bf16_t*)d_ws;   // 147456 bf16 = 294,912 B

    convert_w_kernel<<<144, 256, 0, stream>>>(qkv_w, proj_w, wbuf);
    swin_fused_kernel<<<2048, 384, 0, stream>>>(x, wbuf, qkv_b, proj_b, tbl,
                                                (float*)d_out);
}

// Round 3
// 533.603 us; speedup vs baseline: 1.4796x; 1.4796x over previous
//
#include <hip/hip_runtime.h>

typedef __bf16 bf16_t;
typedef __bf16 bf16x8 __attribute__((ext_vector_type(8)));
typedef __bf16 bf16x4 __attribute__((ext_vector_type(4)));
typedef float  f32x4  __attribute__((ext_vector_type(4)));

#define MFMA16(a,b,c) __builtin_amdgcn_mfma_f32_16x16x32_bf16((a),(b),(c),0,0,0)

// LDS plan (bf16 elems), total 17910 -> 35,820 B -> 4 blocks/CU:
//   region [13056]: x [64][200] ->(barrier)-> vT [192][68] ->(barrier)-> attn [64][200]
//                   ->(barrier)-> proj-out f32 [32][196] (two halves)
//   scratch: per-wave [16][40] chunk (Q/K/P roundtrips, one 16-row band at a time;
//            same-wave DS ordering makes barrier-free reuse safe)
//   bt [1014]: rel-bias table
// Epilogue writes each output pixel as 48 contiguous float4s (768 B): every 128 B
// line is covered by 8 consecutive lanes of ONE store instruction -> no partial-line
// RMW at HBM (round-1/2 showed 3.6-5.8x write amplification from 64 B segments).
#define REG_STRIDE 200
#define VT_STRIDE  68
#define REG_ELEMS  13056
#define SC_STRIDE  40
#define SC_CHUNK   640                        // [16][40]
#define BT_OFF     (REG_ELEMS + 6 * SC_CHUNK) // 16896
#define SMEM_ELEMS (BT_OFF + 1014)            // 17910 elems = 35820 B
#define FSTRIDE    196                        // f32 proj-out stride

// bf16 weights staged in workspace by prep kernel: qkv_w [576*192] then proj_w [192*192]
#define WPROJ_OFF 110592

__global__ void convert_w_kernel(const float* __restrict__ qkv_w,
                                 const float* __restrict__ proj_w,
                                 bf16_t* __restrict__ wb) {
    const int i = (blockIdx.x * 256 + threadIdx.x) * 4;
    float4 f;
    if (i < WPROJ_OFF) f = *(const float4*)(qkv_w + i);
    else               f = *(const float4*)(proj_w + (i - WPROJ_OFF));
    bf16x4 v;
    v[0] = (bf16_t)f.x; v[1] = (bf16_t)f.y; v[2] = (bf16_t)f.z; v[3] = (bf16_t)f.w;
    *(bf16x4*)(wb + i) = v;
}

// 64x32 GEMM over K=192: A-frags from LDS (row-major, REG_STRIDE), B-frags from
// pre-converted bf16 weight rows w0 (ni=0) / w1 (ni=1), prefetch depth 2.
__device__ __forceinline__ void gemm64x32(const bf16_t* __restrict__ xa,
                                          const bf16_t* __restrict__ w0,
                                          const bf16_t* __restrict__ w1,
                                          f32x4 acc[4][2]) {
    bf16x8 b0 = *(const bf16x8*)(w0);
    bf16x8 b1 = *(const bf16x8*)(w1);
    bf16x8 n0 = *(const bf16x8*)(w0 + 32);
    bf16x8 n1 = *(const bf16x8*)(w1 + 32);
    #pragma unroll
    for (int ks = 0; ks < 6; ++ks) {
        bf16x8 m0, m1;
        if (ks < 4) {
            m0 = *(const bf16x8*)(w0 + (ks + 2) * 32);
            m1 = *(const bf16x8*)(w1 + (ks + 2) * 32);
        }
        #pragma unroll
        for (int mi = 0; mi < 4; ++mi) {
            const bf16x8 afr = *(const bf16x8*)(xa + (mi * 16) * REG_STRIDE + ks * 32);
            acc[mi][0] = MFMA16(afr, b0, acc[mi][0]);
            acc[mi][1] = MFMA16(afr, b1, acc[mi][1]);
        }
        b0 = n0; b1 = n1; n0 = m0; n1 = m1;
    }
}

__global__ __launch_bounds__(384, 5)
void swin_fused_kernel(const float* __restrict__ x,
                       const bf16_t* __restrict__ wbuf,
                       const float* __restrict__ qkv_b,
                       const float* __restrict__ proj_b,
                       const float* __restrict__ tbl,
                       float* __restrict__ out)
{
    __shared__ __align__(16) bf16_t smem[SMEM_ELEMS];
    bf16_t* region = smem;
    bf16_t* bt     = smem + BT_OFF;

    const int tid    = threadIdx.x;
    const int lane   = tid & 63;
    const int wave   = tid >> 6;        // == head
    const int lanelo = lane & 15;
    const int quad   = lane >> 4;

    bf16_t* sc = smem + REG_ELEMS + wave * SC_CHUNK;   // per-wave [16][40]

    const int blk = blockIdx.x;
    const int b   = blk >> 8;
    const int wh  = (blk >> 4) & 15;
    const int ww  = blk & 15;
    const int rowbase = wh * 7 + 3;     // shifted (i) -> orig (i+3)%112
    const int colbase = ww * 7 + 3;

    // ---- phase 0: bias table + x window -> LDS bf16 (rows 49..63 zeroed) ----
    for (int i = tid; i < 1014; i += 384) bt[i] = (bf16_t)tbl[i];

    for (int idx = tid; idx < 64 * 48; idx += 384) {
        const int t  = idx / 48;
        const int c4 = (idx - t * 48) * 4;
        bf16x4 v4;
        if (t < 49) {
            int gr = rowbase + t / 7;  if (gr >= 112) gr -= 112;
            int gc = colbase + t % 7;  if (gc >= 112) gc -= 112;
            const float4 f = *(const float4*)(x + (((long)b * 112 + gr) * 112 + gc) * 192 + c4);
            v4[0] = (bf16_t)f.x; v4[1] = (bf16_t)f.y;
            v4[2] = (bf16_t)f.z; v4[3] = (bf16_t)f.w;
        } else {
            v4[0] = (bf16_t)0.0f; v4[1] = (bf16_t)0.0f;
            v4[2] = (bf16_t)0.0f; v4[3] = (bf16_t)0.0f;
        }
        *(bf16x4*)(region + t * REG_STRIDE + c4) = v4;
    }
    __syncthreads();

    // ---- phase 1: per-wave head QKV (each wave computes its own head slice) ----
    const int h = wave;
    const bf16_t* xa = region + lanelo * REG_STRIDE + quad * 8;

    bf16x8 qa[4], kb[4];
    f32x4  vacc[4][2];
    {
        // Q
        {
            const bf16_t* wb = wbuf + (0 * 192 + h * 32) * 192;
            f32x4 acc[4][2] = {};
            gemm64x32(xa, wb + lanelo * 192 + quad * 8, wb + (16 + lanelo) * 192 + quad * 8, acc);
            const float bias0 = qkv_b[0 * 192 + h * 32 + lanelo];
            const float bias1 = qkv_b[0 * 192 + h * 32 + 16 + lanelo];
            #pragma unroll
            for (int mi = 0; mi < 4; ++mi) {
                #pragma unroll
                for (int r = 0; r < 4; ++r) {
                    sc[(quad * 4 + r) * SC_STRIDE + lanelo]      = (bf16_t)(acc[mi][0][r] + bias0);
                    sc[(quad * 4 + r) * SC_STRIDE + 16 + lanelo] = (bf16_t)(acc[mi][1][r] + bias1);
                }
                qa[mi] = *(const bf16x8*)(sc + lanelo * SC_STRIDE + quad * 8);
            }
        }
        // K
        {
            const bf16_t* wb = wbuf + (1 * 192 + h * 32) * 192;
            f32x4 acc[4][2] = {};
            gemm64x32(xa, wb + lanelo * 192 + quad * 8, wb + (16 + lanelo) * 192 + quad * 8, acc);
            const float bias0 = qkv_b[1 * 192 + h * 32 + lanelo];
            const float bias1 = qkv_b[1 * 192 + h * 32 + 16 + lanelo];
            #pragma unroll
            for (int mi = 0; mi < 4; ++mi) {
                #pragma unroll
                for (int r = 0; r < 4; ++r) {
                    sc[(quad * 4 + r) * SC_STRIDE + lanelo]      = (bf16_t)(acc[mi][0][r] + bias0);
                    sc[(quad * 4 + r) * SC_STRIDE + 16 + lanelo] = (bf16_t)(acc[mi][1][r] + bias1);
                }
                kb[mi] = *(const bf16x8*)(sc + lanelo * SC_STRIDE + quad * 8);
            }
        }
        // V (keep acc in regs; written to vT after the barrier)
        {
            const bf16_t* wb = wbuf + (2 * 192 + h * 32) * 192;
            f32x4 acc[4][2] = {};
            gemm64x32(xa, wb + lanelo * 192 + quad * 8, wb + (16 + lanelo) * 192 + quad * 8, acc);
            #pragma unroll
            for (int mi = 0; mi < 4; ++mi) {
                vacc[mi][0] = acc[mi][0];
                vacc[mi][1] = acc[mi][1];
            }
        }
    }
    __syncthreads();   // all x reads done -> region becomes vT

    // vT write: region[dim][token], stride 68; wave h owns dims h*32..h*32+31
    {
        const float bias0 = qkv_b[2 * 192 + h * 32 + lanelo];
        const float bias1 = qkv_b[2 * 192 + h * 32 + 16 + lanelo];
        #pragma unroll
        for (int mi = 0; mi < 4; ++mi)
            #pragma unroll
            for (int r = 0; r < 4; ++r) {
                const int tok = quad * 4 + r + 16 * mi;
                region[(h * 32 + lanelo) * VT_STRIDE + tok]      = (bf16_t)(vacc[mi][0][r] + bias0);
                region[(h * 32 + 16 + lanelo) * VT_STRIDE + tok] = (bf16_t)(vacc[mi][1][r] + bias1);
            }
    }

    // ---- phase 2: S = Q K^T, mask+softmax (per-mi), chunked P roundtrip, PV ----
    f32x4 o_[4][2] = {};
    {
        const float scale = 0.17677669529663687f;   // 32^-0.5

        // per-lane key-column attributes for each ni tile
        int kvalid[4], kch[4], kcw[4], kid[4];
        #pragma unroll
        for (int ni = 0; ni < 4; ++ni) {
            const int col = ni * 16 + lanelo;
            kvalid[ni] = (col < 49);
            const int cc = kvalid[ni] ? col : 48;
            kch[ni] = cc / 7; kcw[ni] = cc - kch[ni] * 7;
            const int gr = wh * 7 + kch[ni], gc = ww * 7 + kcw[ni];
            kid[ni] = (gr < 105 ? 0 : (gr < 109 ? 1 : 2)) * 3 + (gc < 105 ? 0 : (gc < 109 ? 1 : 2));
        }

        // V fragments (own head rows of vT; written by this same wave above)
        const bf16x8 bv00 = *(const bf16x8*)(region + (h * 32 + lanelo) * VT_STRIDE + quad * 8);
        const bf16x8 bv01 = *(const bf16x8*)(region + (h * 32 + 16 + lanelo) * VT_STRIDE + quad * 8);
        const bf16x8 bv10 = *(const bf16x8*)(region + (h * 32 + lanelo) * VT_STRIDE + 32 + quad * 8);
        const bf16x8 bv11 = *(const bf16x8*)(region + (h * 32 + 16 + lanelo) * VT_STRIDE + 32 + quad * 8);

        #pragma unroll
        for (int mi = 0; mi < 4; ++mi) {
            f32x4 s[4];
            #pragma unroll
            for (int ni = 0; ni < 4; ++ni) {
                f32x4 z = {0.f, 0.f, 0.f, 0.f};
                s[ni] = MFMA16(qa[mi], kb[ni], z);
            }
            #pragma unroll
            for (int r = 0; r < 4; ++r) {
                const int row = mi * 16 + quad * 4 + r;
                const int rq  = (row < 49) ? row : 48;
                const int rh  = rq / 7, rw = rq - (rq / 7) * 7;
                const int gqr = wh * 7 + rh, gqc = ww * 7 + rw;
                const int idq = (gqr < 105 ? 0 : (gqr < 109 ? 1 : 2)) * 3 + (gqc < 105 ? 0 : (gqc < 109 ? 1 : 2));
                #pragma unroll
                for (int ni = 0; ni < 4; ++ni) {
                    float v;
                    if (kvalid[ni]) {
                        const int bidx = ((rh - kch[ni] + 6) * 13 + (rw - kcw[ni] + 6)) * 6 + h;
                        v = s[ni][r] * scale + (float)bt[bidx];
                        if (idq != kid[ni]) v -= 100.0f;
                    } else {
                        v = -1e30f;
                    }
                    s[ni][r] = v;
                }
                float m0 = fmaxf(fmaxf(s[0][r], s[1][r]), fmaxf(s[2][r], s[3][r]));
                m0 = fmaxf(m0, __shfl_xor(m0, 1));
                m0 = fmaxf(m0, __shfl_xor(m0, 2));
                m0 = fmaxf(m0, __shfl_xor(m0, 4));
                m0 = fmaxf(m0, __shfl_xor(m0, 8));
                float sum = 0.f;
                #pragma unroll
                for (int ni = 0; ni < 4; ++ni) {
                    const float e = __expf(s[ni][r] - m0);
                    s[ni][r] = e;
                    sum += e;
                }
                sum += __shfl_xor(sum, 1);
                sum += __shfl_xor(sum, 2);
                sum += __shfl_xor(sum, 4);
                sum += __shfl_xor(sum, 8);
                const float rinv = 1.0f / sum;
                // P cols 0..31 (ni=0,1) -> chunk now; keep ni=2,3 normalized in regs
                sc[(quad * 4 + r) * SC_STRIDE + lanelo]      = (bf16_t)(s[0][r] * rinv);
                sc[(quad * 4 + r) * SC_STRIDE + 16 + lanelo] = (bf16_t)(s[1][r] * rinv);
                s[2][r] *= rinv;
                s[3][r] *= rinv;
            }
            {   // PV ks=0
                const bf16x8 ap = *(const bf16x8*)(sc + lanelo * SC_STRIDE + quad * 8);
                o_[mi][0] = MFMA16(ap, bv00, o_[mi][0]);
                o_[mi][1] = MFMA16(ap, bv01, o_[mi][1]);
            }
            #pragma unroll
            for (int r = 0; r < 4; ++r) {
                sc[(quad * 4 + r) * SC_STRIDE + lanelo]      = (bf16_t)s[2][r];
                sc[(quad * 4 + r) * SC_STRIDE + 16 + lanelo] = (bf16_t)s[3][r];
            }
            {   // PV ks=1
                const bf16x8 ap = *(const bf16x8*)(sc + lanelo * SC_STRIDE + quad * 8);
                o_[mi][0] = MFMA16(ap, bv10, o_[mi][0]);
                o_[mi][1] = MFMA16(ap, bv11, o_[mi][1]);
            }
        }
    }
    __syncthreads();   // all vT reads done -> region becomes attn_out

    // attn_out write (C-layout), rows = tokens, stride 200
    #pragma unroll
    for (int mi = 0; mi < 4; ++mi)
        #pragma unroll
        for (int r = 0; r < 4; ++r) {
            const int row = quad * 4 + r + 16 * mi;
            region[row * REG_STRIDE + h * 32 + lanelo]      = (bf16_t)(o_[mi][0][r]);
            region[row * REG_STRIDE + h * 32 + 16 + lanelo] = (bf16_t)(o_[mi][1][r]);
        }
    __syncthreads();

    // ---- phase 3: proj GEMM + bias -> f32 LDS (two 32-token halves) -> full-line
    //      cooperative pixel writes (48 float4 per pixel, contiguous 768 B) ----
    {
        const bf16_t* wb = wbuf + WPROJ_OFF + (wave * 32) * 192;
        f32x4 acc[4][2] = {};
        gemm64x32(xa, wb + lanelo * 192 + quad * 8, wb + (16 + lanelo) * 192 + quad * 8, acc);
        const int o0 = wave * 32 + lanelo;
        const float pb0 = proj_b[o0];
        const float pb1 = proj_b[o0 + 16];
        float* freg = (float*)smem;             // f32 [32][FSTRIDE] view of region
        __syncthreads();                        // all attn-region A-frag reads done
        #pragma unroll
        for (int half = 0; half < 2; ++half) {
            #pragma unroll
            for (int mi = 0; mi < 2; ++mi) {
                const int ami = half * 2 + mi;
                #pragma unroll
                for (int r = 0; r < 4; ++r) {
                    const int row = quad * 4 + r + 16 * mi;   // buffer row = token - 32*half
                    freg[row * FSTRIDE + o0]      = acc[ami][0][r] + pb0;
                    freg[row * FSTRIDE + o0 + 16] = acc[ami][1][r] + pb1;
                }
            }
            __syncthreads();
            const int lim = half ? 816 : 1536;  // (17 or 32 pixels) * 48 float4
            for (int idx = tid; idx < lim; idx += 384) {
                const int t  = idx / 48;
                const int cc = (idx - t * 48) * 4;
                const int tok = half * 32 + t;
                int gr = rowbase + tok / 7;  if (gr >= 112) gr -= 112;
                int gc = colbase + tok % 7;  if (gc >= 112) gc -= 112;
                const float4 v = *(const float4*)(freg + t * FSTRIDE + cc);
                *(float4*)(out + (((long)b * 112 + gr) * 112 + gc) * 192 + cc) = v;
            }
            if (!half) __syncthreads();
        }
    }
}

extern "C" void kernel_launch(void* const* d_in, const int* in_sizes, int n_in,
                              void* d_out, int out_size, void* d_ws, size_t ws_size,
                              hipStream_t stream) {
    const float* x      = (const float*)d_in[0];
    const float* qkv_w  = (const float*)d_in[1];
    const float* qkv_b  = (const float*)d_in[2];
    const float* proj_w = (const float*)d_in[3];
    const float* proj_b = (const float*)d_in[4];
    const float* tbl    = (const float*)d_in[5];
    bf16_t* wbuf = (bf16_t*)d_ws;   // 147456 bf16 = 294,912 B

    convert_w_kernel<<<144, 256, 0, stream>>>(qkv_w, proj_w, wbuf);
    swin_fused_kernel<<<4096, 384, 0, stream>>>(x, wbuf, qkv_b, proj_b, tbl,
                                                (float*)d_out);
}